// Round 1
// baseline (707.269 us; speedup 1.0000x reference)
//
#include <hip/hip_runtime.h>

// Problem constants (from reference)
#define N_NODES 100000
#define D_FEAT  64
#define N_EDGES 3200000
#define GAMMA   0.5f

// out[0 .. N*D)      = -GAMMA * h          (node part init; scatter adds on top)
// out[N*D .. +E)     = 0                   (edge part of ODE output)
__global__ void init_out_kernel(const float* __restrict__ x,
                                float* __restrict__ out,
                                int nd, int total) {
    int i = blockIdx.x * blockDim.x + threadIdx.x;
    if (i < nd) {
        out[i] = -GAMMA * x[i];
    } else if (i < total) {
        out[i] = 0.0f;
    }
}

// One 64-lane wave per edge; lane = feature dim d.
// h[src]*e scatter-summed into out[dst] via f32 atomics.
__global__ void edge_scatter_kernel(const float* __restrict__ h,
                                    const float* __restrict__ e,
                                    const int* __restrict__ src,
                                    const int* __restrict__ dst,
                                    float* __restrict__ out) {
    long long idx = (long long)blockIdx.x * blockDim.x + threadIdx.x;
    int edge = (int)(idx >> 6);     // 64 lanes per edge
    int d    = (int)(idx & 63);
    if (edge >= N_EDGES) return;

    int   s = src[edge];            // wave-uniform (broadcast load)
    int   t = dst[edge];
    float w = e[edge];

    float m = h[(long long)s * D_FEAT + d] * w;   // coalesced 256B row read
    atomicAdd(&out[(long long)t * D_FEAT + d], m);
}

extern "C" void kernel_launch(void* const* d_in, const int* in_sizes, int n_in,
                              void* d_out, int out_size, void* d_ws, size_t ws_size,
                              hipStream_t stream) {
    // inputs per setup_inputs(): t, x, src, dst
    const float* x   = (const float*)d_in[1];
    const int*   src = (const int*)d_in[2];
    const int*   dst = (const int*)d_in[3];
    float*       out = (float*)d_out;

    const int nd    = N_NODES * D_FEAT;          // 6,400,000
    const int total = nd + N_EDGES;              // 9,600,000

    // 1) init output (overwrites poison every call -> deterministic base)
    {
        int block = 256;
        int grid  = (total + block - 1) / block;
        init_out_kernel<<<grid, block, 0, stream>>>(x, out, nd, total);
    }

    // 2) scatter-sum messages
    {
        long long threads = (long long)N_EDGES * 64;
        int block = 256;
        long long grid = (threads + block - 1) / block;   // 800,000 blocks
        edge_scatter_kernel<<<(int)grid, block, 0, stream>>>(
            x /* h = first N*D of x */,
            x + nd /* e */,
            src, dst, out);
    }
}